// Round 1
// baseline (170.474 us; speedup 1.0000x reference)
//
#include <hip/hip_runtime.h>

// (B, Lq, Lk, D, C, KW) = (8, 1024, 1024, 512, 512, 3)
//
// Algebraic refactor vs previous version:
//   a[b,i,j] = sum_d q[b,i,d] * V[b,j,d] + biasq[b,i] + t[b,j] + bias_b
//   V[b,j,d] = sum_{c,w} W[d, c*3+w] * kpad[b, j+w, c]     (12.9 GF, K=1536)
//   out      = q @ V^T per batch                           ( 8.6 GF, K=512)
//   t[b,j]   = sum_{c,w} b_kernel[c*3+w] * kpad[b, j+w, c] (tiny, in cvt_all)
// Total 21.5 GF vs old 38.7 GF; intermediate 8 MB (V) vs 24 MB (G).

typedef __attribute__((ext_vector_type(8))) short s8vec;    // 8 x bf16 (4 VGPRs)
typedef __attribute__((ext_vector_type(4))) float floatx4;  // MFMA accumulator

__device__ __forceinline__ unsigned short f2bf(float f) {
    union { float f; unsigned u; } v; v.f = f;
    unsigned r = (v.u + 0x7FFFu + ((v.u >> 16) & 1u)) >> 16;
    return (unsigned short)r;
}

__device__ __forceinline__ void gl2lds16(const void* g, void* l) {
    __builtin_amdgcn_global_load_lds(
        (__attribute__((address_space(1))) void*)(g),
        (__attribute__((address_space(3))) void*)(l), 16, 0, 0);
}

// ---- fused: q->bf16, k->padded bf16, zero pad, biasq = q@W_bias+b_bias,
//      W permute -> Wt2[d][w*512+c] bf16, and t[b,j] = conv(k, b_kernel) ----
__global__ void cvt_all(const float* __restrict__ q, const float* __restrict__ k,
                        unsigned short* __restrict__ qbf, unsigned short* __restrict__ kp,
                        const float* __restrict__ Wb, const float* __restrict__ b_bias,
                        float* __restrict__ biasq,
                        const float* __restrict__ W, unsigned short* __restrict__ Wt2,
                        const float* __restrict__ b_kernel, float* __restrict__ tj) {
    int blk = blockIdx.x;
    if (blk < 4104) {
        int t = blk * 256 + threadIdx.x;
        if (t < 524288) {                       // q: 8*1024*512 / 8
            const float4* p = (const float4*)q + 2 * (size_t)t;
            float4 a = p[0], b = p[1];
            union { unsigned short s[8]; uint4 v; } o;
            o.s[0]=f2bf(a.x); o.s[1]=f2bf(a.y); o.s[2]=f2bf(a.z); o.s[3]=f2bf(a.w);
            o.s[4]=f2bf(b.x); o.s[5]=f2bf(b.y); o.s[6]=f2bf(b.z); o.s[7]=f2bf(b.w);
            ((uint4*)qbf)[t] = o.v;
        } else if (t < 1048576) {               // k -> padded kp (row j+1)
            int e8 = t - 524288;
            size_t e = (size_t)e8 * 8;
            int b = e8 >> 16;
            int j = (e8 >> 6) & 1023;
            int c = (e8 & 63) * 8;
            const float4* p = (const float4*)(k + e);
            float4 a = p[0], bb = p[1];
            union { unsigned short s[8]; uint4 v; } o;
            o.s[0]=f2bf(a.x); o.s[1]=f2bf(a.y); o.s[2]=f2bf(a.z); o.s[3]=f2bf(a.w);
            o.s[4]=f2bf(bb.x); o.s[5]=f2bf(bb.y); o.s[6]=f2bf(bb.z); o.s[7]=f2bf(bb.w);
            *(uint4*)(kp + ((size_t)(b * 1028 + j + 1) * 512 + c)) = o.v;
        } else if (t < 1050624) {               // zero pad rows 0, 1025..1027
            int z = t - 1048576;
            int b = z >> 8, r = (z >> 6) & 3, ch = z & 63;
            int row = r ? (1024 + r) : 0;
            *(uint4*)(kp + ((size_t)(b * 1028 + row) * 512 + ch * 8)) = make_uint4(0u,0u,0u,0u);
        }
    } else if (blk < 6152) {                    // biasq: one wave per row
        int row  = (blk - 4104) * 4 + (threadIdx.x >> 6);
        int lane = threadIdx.x & 63;
        const float4* qr = (const float4*)(q + (size_t)row * 512) + lane * 2;
        const float4* wb = (const float4*)Wb + lane * 2;
        float4 a0 = qr[0], a1 = qr[1], b0 = wb[0], b1 = wb[1];
        float s = a0.x*b0.x + a0.y*b0.y + a0.z*b0.z + a0.w*b0.w
                + a1.x*b1.x + a1.y*b1.y + a1.z*b1.z + a1.w*b1.w;
        #pragma unroll
        for (int off = 32; off > 0; off >>= 1) s += __shfl_down(s, off);
        if (lane == 0) biasq[row] = s + b_bias[0];
    } else if (blk < 6536) {                    // Wt2[d][w*512+c] = W[d][c*3+w]
        int e = (blk - 6152) * 256 + threadIdx.x;     // 0..98303
        int d = e / 192;
        int rem = e - d * 192;
        int w = rem >> 6, c0 = (rem & 63) * 8;
        const float* wrow = W + (size_t)d * 1536;
        union { unsigned short s[8]; uint4 v; } o;
        #pragma unroll
        for (int i = 0; i < 8; i++) o.s[i] = f2bf(wrow[(c0 + i) * 3 + w]);
        *(uint4*)(Wt2 + (size_t)d * 1536 + w * 512 + c0) = o.v;
    } else {                                    // t[b,j]: one wave per (b,j)
        int row  = (blk - 6536) * 4 + (threadIdx.x >> 6);   // 0..8191
        int lane = threadIdx.x & 63;
        int b = row >> 10, j = row & 1023;
        int c0 = lane * 8;
        const float* kb = k + (size_t)b * 1024 * 512;
        float s = 0.0f;
        #pragma unroll
        for (int w = 0; w < 3; w++) {
            int r = j + w - 1;
            if (r >= 0 && r < 1024) {
                const float4* kr = (const float4*)(kb + (size_t)r * 512) + lane * 2;
                float4 a0 = kr[0], a1 = kr[1];
                const float* bk = b_kernel + w;
                s += a0.x * bk[(c0+0)*3] + a0.y * bk[(c0+1)*3]
                   + a0.z * bk[(c0+2)*3] + a0.w * bk[(c0+3)*3]
                   + a1.x * bk[(c0+4)*3] + a1.y * bk[(c0+5)*3]
                   + a1.z * bk[(c0+6)*3] + a1.w * bk[(c0+7)*3];
            }
        }
        #pragma unroll
        for (int off = 32; off > 0; off >>= 1) s += __shfl_down(s, off);
        if (lane == 0) tj[row] = s;
    }
}

// ---- Phase V: V[b*1024+j][d] = bf16( kwin_flat[b,j,:] @ Wt2[d,:]^T )
//      A rows are kp + (b*1028+j)*512, length K=1536 (overlapping windows).
//      128m x 64n tiles, 4 waves (2x2), wave tile 64x32, grid 512.
//      XCD = batch: kp[b] (1 MB) + Wt2 (1.5 MB) resident per-XCD L2. ----
__global__ __launch_bounds__(256) void gemm_V(const unsigned short* __restrict__ kp,
                                              const unsigned short* __restrict__ Wt2,
                                              unsigned short* __restrict__ V) {
    __shared__ unsigned short lds_a[128 * 32];  // 8 KB
    __shared__ unsigned short lds_b[64 * 32];   // 4 KB
    int g = blockIdx.x;                 // 0..511
    int b = g & 7, slot = g >> 3;       // slot 0..63
    int j0 = (slot >> 3) * 128;         // 8 m-tiles per batch
    int n0 = (slot & 7) * 64;           // 8 n-tiles
    int tid = threadIdx.x, wid = tid >> 6, lane = tid & 63;
    int wm = wid >> 1, wn = wid & 1;
    const unsigned short* kpb = kp + (size_t)(b * 1028 + j0) * 512;
    floatx4 acc[4][2] = {};

    for (int kk = 0; kk < 1536; kk += 32) {
        #pragma unroll
        for (int s = 0; s < 3; ++s) {
            int t = wid * 3 + s;        // 0..11, wave-uniform
            if (t < 8) {                // A: 128 kp-window rows
                const unsigned short* ga = kpb + (size_t)(t * 16 + (lane >> 2)) * 512 + kk + (lane & 3) * 8;
                gl2lds16(ga, (char*)lds_a + t * 1024);
            } else {                    // B: 64 Wt2 rows (d)
                int u = t - 8;
                const unsigned short* gb = Wt2 + (size_t)(n0 + u * 16 + (lane >> 2)) * 1536 + kk + (lane & 3) * 8;
                gl2lds16(gb, (char*)lds_b + u * 1024);
            }
        }
        __syncthreads();
        int ra = lane & 15, q8 = (lane >> 4) * 8;
        s8vec af[4], bfr[2];
        #pragma unroll
        for (int mi = 0; mi < 4; mi++)
            af[mi] = *(const s8vec*)(lds_a + (wm * 64 + mi * 16 + ra) * 32 + q8);
        #pragma unroll
        for (int ni = 0; ni < 2; ni++)
            bfr[ni] = *(const s8vec*)(lds_b + (wn * 32 + ni * 16 + ra) * 32 + q8);
        #pragma unroll
        for (int mi = 0; mi < 4; mi++)
            #pragma unroll
            for (int ni = 0; ni < 2; ni++)
                acc[mi][ni] = __builtin_amdgcn_mfma_f32_16x16x32_bf16(af[mi], bfr[ni], acc[mi][ni], 0, 0, 0);
        __syncthreads();
    }

    int cl = lane & 15, qd = lane >> 4;
    #pragma unroll
    for (int mi = 0; mi < 4; mi++) {
        #pragma unroll
        for (int ni = 0; ni < 2; ni++) {
            int col = n0 + wn * 32 + ni * 16 + cl;
            #pragma unroll
            for (int r = 0; r < 4; r++) {
                int m_g = b * 1024 + j0 + wm * 64 + mi * 16 + qd * 4 + r;
                V[(size_t)m_g * 512 + col] = f2bf(acc[mi][ni][r]);
            }
        }
    }
}

// ---- Phase B': out[b,i,j] = sum_d qbf[b,i,d]*V[b,j,d] + biasq[b,i] + t[b,j] + bias_b
//      128x128 tiles (m97 shape), 4 waves, grid 512, XCD = batch
//      (qbf[b] 1 MB + V[b] 1 MB per-XCD L2 resident). ----
__global__ __launch_bounds__(256) void gemm_QV(const unsigned short* __restrict__ qbf,
                                               const unsigned short* __restrict__ V,
                                               const float* __restrict__ biasq,
                                               const float* __restrict__ tj,
                                               const float* __restrict__ bias_b,
                                               float* __restrict__ out) {
    __shared__ unsigned short lds_a[128 * 32];
    __shared__ unsigned short lds_b[128 * 32];
    int g = blockIdx.x;                 // 0..511
    int b = g & 7, slot = g >> 3;       // slot 0..63
    int i0 = (slot >> 3) * 128;
    int j0 = (slot & 7) * 128;
    int tid = threadIdx.x, wid = tid >> 6, lane = tid & 63;
    int wm = wid >> 1, wn = wid & 1;
    const unsigned short* Ab = qbf + (size_t)b * 1024 * 512;
    const unsigned short* Bb = V   + (size_t)b * 1024 * 512;
    floatx4 acc[4][4] = {};

    for (int kk = 0; kk < 512; kk += 32) {
        #pragma unroll
        for (int s = 0; s < 2; ++s) {
            int t = wid * 2 + s;        // 0..7, wave-uniform
            const unsigned short* ga = Ab + (size_t)(i0 + t * 16 + (lane >> 2)) * 512 + kk + (lane & 3) * 8;
            gl2lds16(ga, (char*)lds_a + t * 1024);
            const unsigned short* gb = Bb + (size_t)(j0 + t * 16 + (lane >> 2)) * 512 + kk + (lane & 3) * 8;
            gl2lds16(gb, (char*)lds_b + t * 1024);
        }
        __syncthreads();
        int ra = lane & 15, q8 = (lane >> 4) * 8;
        s8vec af[4], bfr[4];
        #pragma unroll
        for (int mi = 0; mi < 4; mi++)
            af[mi] = *(const s8vec*)(lds_a + (wm * 64 + mi * 16 + ra) * 32 + q8);
        #pragma unroll
        for (int ni = 0; ni < 4; ni++)
            bfr[ni] = *(const s8vec*)(lds_b + (wn * 64 + ni * 16 + ra) * 32 + q8);
        #pragma unroll
        for (int mi = 0; mi < 4; mi++)
            #pragma unroll
            for (int ni = 0; ni < 4; ni++)
                acc[mi][ni] = __builtin_amdgcn_mfma_f32_16x16x32_bf16(af[mi], bfr[ni], acc[mi][ni], 0, 0, 0);
        __syncthreads();
    }

    int cl = lane & 15, qd = lane >> 4;
    float bb = bias_b[0];
    float tv[4];
    #pragma unroll
    for (int ni = 0; ni < 4; ni++)
        tv[ni] = tj[b * 1024 + j0 + wn * 64 + ni * 16 + cl];
    #pragma unroll
    for (int mi = 0; mi < 4; mi++) {
        #pragma unroll
        for (int r = 0; r < 4; r++) {
            int i_g = i0 + wm * 64 + mi * 16 + qd * 4 + r;
            float bv = biasq[b * 1024 + i_g] + bb;
            float* orow = out + ((size_t)(b * 1024 + i_g)) * 1024 + j0;
            #pragma unroll
            for (int ni = 0; ni < 4; ni++) {
                int j_loc = wn * 64 + ni * 16 + cl;
                orow[j_loc] = acc[mi][ni][r] + bv + tv[ni];
            }
        }
    }
}

extern "C" void kernel_launch(void* const* d_in, const int* in_sizes, int n_in,
                              void* d_out, int out_size, void* d_ws, size_t ws_size,
                              hipStream_t stream) {
    const float* q        = (const float*)d_in[0];  // (8,1024,512)
    const float* k        = (const float*)d_in[1];  // (8,1024,512)
    const float* W_kernel = (const float*)d_in[2];  // (512,1536)
    const float* b_kernel = (const float*)d_in[3];  // (1536,)
    const float* W_bias   = (const float*)d_in[4];  // (512,1)
    const float* b_bias   = (const float*)d_in[5];  // (1,)
    const float* bias_b   = (const float*)d_in[6];  // (1,)
    float* out = (float*)d_out;                     // (8,1024,1024)

    // workspace carve (bytes):
    //   q_bf 8M | kp 8.03M + 16K headroom | Wt2 1.5M | V 8M | biasq 32K | tj 32K
    char* ws = (char*)d_ws;
    unsigned short* q_bf = (unsigned short*)(ws);
    unsigned short* kp   = (unsigned short*)(ws + 8388608);
    unsigned short* Wt2  = (unsigned short*)(ws + 8388608 + 8421376 + 16384);
    unsigned short* V    = (unsigned short*)(ws + 8388608 + 8421376 + 16384 + 1572864);
    float*          bsq  = (float*)(ws + 8388608 + 8421376 + 16384 + 1572864 + 8388608);
    float*          tj   = (float*)(ws + 8388608 + 8421376 + 16384 + 1572864 + 8388608 + 32768);

    cvt_all<<<8584, 256, 0, stream>>>(q, k, q_bf, kp, W_bias, b_bias, bsq, W_kernel, Wt2, b_kernel, tj);
    gemm_V<<<512, 256, 0, stream>>>(kp, Wt2, V);
    gemm_QV<<<512, 256, 0, stream>>>(q_bf, V, bsq, tj, bias_b, out);
}

// Round 3
// 138.258 us; speedup vs baseline: 1.2330x; 1.2330x over previous
//
#include <hip/hip_runtime.h>

// (B, Lq, Lk, D, C, KW) = (8, 1024, 1024, 512, 512, 3)
//
// Algebra:
//   out[b,i,j] = q[i]·(V[b,j] + W_bias) + t[b,j] + b_bias + bias_b
//   V[b,j,d]   = sum_{c,w} W[d, c*3+w] * kpad[b, j+w, c]        (K=1536 GEMM)
//   t[b,j]     = V-column 512, via Wt2 row 512 = permuted b_kernel
// Wt2 is 576 x 1536 bf16: rows 0..511 = W permuted, row 512 = b_kernel
// permuted, rows 513..575 = zeros (N-tile padding). V is 8192 x 576 bf16.

typedef __attribute__((ext_vector_type(8))) short s8vec;    // 8 x bf16 (4 VGPRs)
typedef __attribute__((ext_vector_type(4))) float floatx4;  // MFMA accumulator

__device__ __forceinline__ unsigned short f2bf(float f) {
    union { float f; unsigned u; } v; v.f = f;
    unsigned r = (v.u + 0x7FFFu + ((v.u >> 16) & 1u)) >> 16;
    return (unsigned short)r;
}

__device__ __forceinline__ float bf2f(unsigned short s) {
    union { unsigned u; float f; } v; v.u = ((unsigned)s) << 16;
    return v.f;
}

__device__ __forceinline__ void gl2lds16(const void* g, void* l) {
    __builtin_amdgcn_global_load_lds(
        (__attribute__((address_space(1))) void*)(g),
        (__attribute__((address_space(3))) void*)(l), 16, 0, 0);
}

// ---- fused conversions: q->bf16, k->padded bf16 (+zero pad rows),
//      W -> Wt2[d][w*512+c] bf16 (576 rows, row 512 = b_kernel, 513+ = 0) ----
__global__ void cvt_all(const float* __restrict__ q, const float* __restrict__ k,
                        unsigned short* __restrict__ qbf, unsigned short* __restrict__ kp,
                        const float* __restrict__ W, unsigned short* __restrict__ Wt2,
                        const float* __restrict__ b_kernel) {
    int blk = blockIdx.x;
    if (blk < 4104) {
        int t = blk * 256 + threadIdx.x;
        if (t < 524288) {                       // q: 8*1024*512 / 8
            const float4* p = (const float4*)q + 2 * (size_t)t;
            float4 a = p[0], b = p[1];
            union { unsigned short s[8]; uint4 v; } o;
            o.s[0]=f2bf(a.x); o.s[1]=f2bf(a.y); o.s[2]=f2bf(a.z); o.s[3]=f2bf(a.w);
            o.s[4]=f2bf(b.x); o.s[5]=f2bf(b.y); o.s[6]=f2bf(b.z); o.s[7]=f2bf(b.w);
            ((uint4*)qbf)[t] = o.v;
        } else if (t < 1048576) {               // k -> padded kp (row j+1)
            int e8 = t - 524288;
            size_t e = (size_t)e8 * 8;
            int b = e8 >> 16;
            int j = (e8 >> 6) & 1023;
            int c = (e8 & 63) * 8;
            const float4* p = (const float4*)(k + e);
            float4 a = p[0], bb = p[1];
            union { unsigned short s[8]; uint4 v; } o;
            o.s[0]=f2bf(a.x); o.s[1]=f2bf(a.y); o.s[2]=f2bf(a.z); o.s[3]=f2bf(a.w);
            o.s[4]=f2bf(bb.x); o.s[5]=f2bf(bb.y); o.s[6]=f2bf(bb.z); o.s[7]=f2bf(bb.w);
            *(uint4*)(kp + ((size_t)(b * 1028 + j + 1) * 512 + c)) = o.v;
        } else if (t < 1050624) {               // zero pad rows 0, 1025..1027
            int z = t - 1048576;
            int b = z >> 8, r = (z >> 6) & 3, ch = z & 63;
            int row = r ? (1024 + r) : 0;
            *(uint4*)(kp + ((size_t)(b * 1028 + row) * 512 + ch * 8)) = make_uint4(0u,0u,0u,0u);
        }
    } else if (blk < 4616) {                    // Wt2 rows 0..511: one d-row per block
        __shared__ float ldsw[1536];
        int d = blk - 4104;
        const float4* wrow = (const float4*)(W + (size_t)d * 1536);
        for (int e = threadIdx.x; e < 384; e += 256) {
            float4 v = wrow[e];
            float va[4] = { v.x, v.y, v.z, v.w };
            #pragma unroll
            for (int i = 0; i < 4; i++) {
                int idx = e * 4 + i;            // idx = c*3 + w
                int c = idx / 3, w = idx - c * 3;
                ldsw[w * 512 + c] = va[i];
            }
        }
        __syncthreads();
        for (int p = threadIdx.x; p < 192; p += 256) {
            union { unsigned short s[8]; uint4 v; } o;
            #pragma unroll
            for (int i = 0; i < 8; i++) o.s[i] = f2bf(ldsw[p * 8 + i]);
            *(uint4*)(Wt2 + (size_t)d * 1536 + p * 8) = o.v;
        }
    } else {                                    // Wt2 rows 512..575
        int u = (blk - 4616) * 256 + threadIdx.x;   // 0..12287
        int row = 512 + u / 192;
        int p = u - (u / 192) * 192;                // 0..191
        union { unsigned short s[8]; uint4 v; } o;
        if (row == 512) {
            #pragma unroll
            for (int i = 0; i < 8; i++) {
                int lin = p * 8 + i;                // w*512 + c
                int w = lin >> 9, c = lin & 511;
                o.s[i] = f2bf(b_kernel[c * 3 + w]);
            }
        } else {
            o.v = make_uint4(0u, 0u, 0u, 0u);
        }
        *(uint4*)(Wt2 + (size_t)row * 1536 + p * 8) = o.v;
    }
}

// ---- Phase V: V[b*1024+j][n] = bf16( kwin_flat[b,j,:] @ Wt2[n,:]^T + Wb[n] )
//      n in [0,576): 512 d-cols (+W_bias) and col 512 = t[b,j].
//      128m x 64n tiles, 4 waves (2x2), wave tile 64x32, grid 576.
//      T3-minimum dbuf: STAGE(next) || compute(cur), one barrier/K-step. ----
__global__ __launch_bounds__(256) void gemm_V(const unsigned short* __restrict__ kp,
                                              const unsigned short* __restrict__ Wt2,
                                              const float* __restrict__ Wbias,
                                              unsigned short* __restrict__ V) {
    __shared__ unsigned short lds_a[2][128 * 32];   // 2 x 8 KB
    __shared__ unsigned short lds_b[2][64 * 32];    // 2 x 4 KB
    int g = blockIdx.x;                 // 0..575
    int b = g & 7, slot = g >> 3;       // slot 0..71
    int j0 = (slot / 9) * 128;          // 8 m-tiles per batch
    int n0 = (slot % 9) * 64;           // 9 n-tiles (d 0..511, then t/zeros)
    int tid = threadIdx.x, wid = tid >> 6, lane = tid & 63;
    int wm = wid >> 1, wn = wid & 1;
    int arow = lane >> 2, acol = (lane & 3) * 8;
    const unsigned short* kpb = kp + (size_t)(b * 1028 + j0) * 512;
    floatx4 acc[4][2] = {};

    auto STAGE = [&](int buf, int kk) {
        #pragma unroll
        for (int s = 0; s < 3; ++s) {
            int t = wid * 3 + s;        // 0..11, wave-uniform
            if (t < 8) {
                const unsigned short* ga = kpb + (size_t)(t * 16 + arow) * 512 + kk + acol;
                gl2lds16(ga, (char*)lds_a[buf] + t * 1024);
            } else {
                int u = t - 8;
                const unsigned short* gb = Wt2 + (size_t)(n0 + u * 16 + arow) * 1536 + kk + acol;
                gl2lds16(gb, (char*)lds_b[buf] + u * 1024);
            }
        }
    };

    STAGE(0, 0);
    __syncthreads();
    int cur = 0;
    int ra = lane & 15, q8 = (lane >> 4) * 8;
    for (int kt = 0; kt < 48; ++kt) {
        if (kt < 47) STAGE(cur ^ 1, (kt + 1) * 32);
        s8vec af[4], bfr[2];
        #pragma unroll
        for (int mi = 0; mi < 4; mi++)
            af[mi] = *(const s8vec*)(&lds_a[cur][(wm * 64 + mi * 16 + ra) * 32 + q8]);
        #pragma unroll
        for (int ni = 0; ni < 2; ni++)
            bfr[ni] = *(const s8vec*)(&lds_b[cur][(wn * 32 + ni * 16 + ra) * 32 + q8]);
        #pragma unroll
        for (int mi = 0; mi < 4; mi++)
            #pragma unroll
            for (int ni = 0; ni < 2; ni++)
                acc[mi][ni] = __builtin_amdgcn_mfma_f32_16x16x32_bf16(af[mi], bfr[ni], acc[mi][ni], 0, 0, 0);
        if (kt < 47) { __syncthreads(); cur ^= 1; }
    }

    int cl = lane & 15, qd = lane >> 4;
    #pragma unroll
    for (int mi = 0; mi < 4; mi++) {
        #pragma unroll
        for (int ni = 0; ni < 2; ni++) {
            int col = n0 + wn * 32 + ni * 16 + cl;
            float wb = (col < 512) ? Wbias[col] : 0.0f;
            #pragma unroll
            for (int r = 0; r < 4; r++) {
                int m_g = b * 1024 + j0 + wm * 64 + mi * 16 + qd * 4 + r;
                V[(size_t)m_g * 576 + col] = f2bf(acc[mi][ni][r] + wb);
            }
        }
    }
}

// ---- Phase B': out[b,i,j] = sum_d qbf[b,i,d]*V[b,j,d] + t[b,j] + b_bias + bias_b
//      128x128 tiles, 4 waves, grid 512, XCD = batch, dbuf 1-barrier. ----
__global__ __launch_bounds__(256) void gemm_QV(const unsigned short* __restrict__ qbf,
                                               const unsigned short* __restrict__ V,
                                               const float* __restrict__ b_bias,
                                               const float* __restrict__ bias_b,
                                               float* __restrict__ out) {
    __shared__ unsigned short lds_a[2][128 * 32];   // 2 x 8 KB
    __shared__ unsigned short lds_b[2][128 * 32];   // 2 x 8 KB
    int g = blockIdx.x;                 // 0..511
    int b = g & 7, slot = g >> 3;       // slot 0..63
    int i0 = (slot >> 3) * 128;
    int j0 = (slot & 7) * 128;
    int tid = threadIdx.x, wid = tid >> 6, lane = tid & 63;
    int wm = wid >> 1, wn = wid & 1;
    int arow = lane >> 2, acol = (lane & 3) * 8;
    const unsigned short* Ab = qbf + (size_t)b * 1024 * 512;
    const unsigned short* Bb = V + (size_t)b * 1024 * 576;
    floatx4 acc[4][4] = {};

    auto STAGE = [&](int buf, int kk) {
        #pragma unroll
        for (int s = 0; s < 2; ++s) {
            int t = wid * 2 + s;        // 0..7, wave-uniform
            const unsigned short* ga = Ab + (size_t)(i0 + t * 16 + arow) * 512 + kk + acol;
            gl2lds16(ga, (char*)lds_a[buf] + t * 1024);
            const unsigned short* gb = Bb + (size_t)(j0 + t * 16 + arow) * 576 + kk + acol;
            gl2lds16(gb, (char*)lds_b[buf] + t * 1024);
        }
    };

    STAGE(0, 0);
    __syncthreads();
    int cur = 0;
    int ra = lane & 15, q8 = (lane >> 4) * 8;
    for (int kt = 0; kt < 16; ++kt) {
        if (kt < 15) STAGE(cur ^ 1, (kt + 1) * 32);
        s8vec af[4], bfr[4];
        #pragma unroll
        for (int mi = 0; mi < 4; mi++)
            af[mi] = *(const s8vec*)(&lds_a[cur][(wm * 64 + mi * 16 + ra) * 32 + q8]);
        #pragma unroll
        for (int ni = 0; ni < 4; ni++)
            bfr[ni] = *(const s8vec*)(&lds_b[cur][(wn * 64 + ni * 16 + ra) * 32 + q8]);
        #pragma unroll
        for (int mi = 0; mi < 4; mi++)
            #pragma unroll
            for (int ni = 0; ni < 4; ni++)
                acc[mi][ni] = __builtin_amdgcn_mfma_f32_16x16x32_bf16(af[mi], bfr[ni], acc[mi][ni], 0, 0, 0);
        if (kt < 15) { __syncthreads(); cur ^= 1; }
    }

    int cl = lane & 15, qd = lane >> 4;
    float bbsum = b_bias[0] + bias_b[0];
    float tv[4];
    #pragma unroll
    for (int ni = 0; ni < 4; ni++) {
        int j_loc = wn * 64 + ni * 16 + cl;
        tv[ni] = bf2f(V[((size_t)(b * 1024 + j0 + j_loc)) * 576 + 512]) + bbsum;
    }
    #pragma unroll
    for (int mi = 0; mi < 4; mi++) {
        #pragma unroll
        for (int r = 0; r < 4; r++) {
            int i_g = i0 + wm * 64 + mi * 16 + qd * 4 + r;
            float* orow = out + ((size_t)(b * 1024 + i_g)) * 1024 + j0;
            #pragma unroll
            for (int ni = 0; ni < 4; ni++) {
                int j_loc = wn * 64 + ni * 16 + cl;
                orow[j_loc] = acc[mi][ni][r] + tv[ni];
            }
        }
    }
}

extern "C" void kernel_launch(void* const* d_in, const int* in_sizes, int n_in,
                              void* d_out, int out_size, void* d_ws, size_t ws_size,
                              hipStream_t stream) {
    const float* q        = (const float*)d_in[0];  // (8,1024,512)
    const float* k        = (const float*)d_in[1];  // (8,1024,512)
    const float* W_kernel = (const float*)d_in[2];  // (512,1536)
    const float* b_kernel = (const float*)d_in[3];  // (1536,)
    const float* W_bias   = (const float*)d_in[4];  // (512,1)
    const float* b_bias   = (const float*)d_in[5];  // (1,)
    const float* bias_b   = (const float*)d_in[6];  // (1,)
    float* out = (float*)d_out;                     // (8,1024,1024)

    // workspace carve (bytes):
    //   q_bf 8M | kp 8.03M + 16K headroom | Wt2 576*1536*2 = 1.69M | V 8192*576*2 = 9M
    char* ws = (char*)d_ws;
    unsigned short* q_bf = (unsigned short*)(ws);
    unsigned short* kp   = (unsigned short*)(ws + 8388608);
    unsigned short* Wt2  = (unsigned short*)(ws + 8388608 + 8421376 + 16384);
    unsigned short* V    = (unsigned short*)(ws + 8388608 + 8421376 + 16384 + 1769472);

    cvt_all<<<4664, 256, 0, stream>>>(q, k, q_bf, kp, W_kernel, Wt2, b_kernel);
    gemm_V<<<576, 256, 0, stream>>>(kp, Wt2, W_bias, V);
    gemm_QV<<<512, 256, 0, stream>>>(q_bf, V, b_bias, bias_b, out);
}

// Round 4
// 133.417 us; speedup vs baseline: 1.2778x; 1.0363x over previous
//
#include <hip/hip_runtime.h>

// (B, Lq, Lk, D, C, KW) = (8, 1024, 1024, 512, 512, 3)
//
// Algebra:
//   out[b,i,j] = q[i]·(V[b,j] + W_bias) + t[b,j] + b_bias + bias_b
//   V[b,j,d]   = sum_{c,w} W[d, c*3+w] * kpad[b, j+w, c]     (K=1536 GEMM, bf16)
//   t[b,j]     = sum_{c,w} b_kernel[c*3+w] * kpad[b, j+w, c] (f32, in cvt_all)
// Wt2 is 512 x 1536 bf16 (W permuted to [d][w*512+c]).  V is 8192 x 512 bf16.
// Both GEMMs: BK=64 double-buffered, one barrier per K-step, XOR-swizzled LDS
// (linear gl2lds dest + inverse-swizzled global source + swizzled ds_read).

typedef __attribute__((ext_vector_type(8))) short s8vec;    // 8 x bf16 (4 VGPRs)
typedef __attribute__((ext_vector_type(4))) float floatx4;  // MFMA accumulator

__device__ __forceinline__ unsigned short f2bf(float f) {
    union { float f; unsigned u; } v; v.f = f;
    unsigned r = (v.u + 0x7FFFu + ((v.u >> 16) & 1u)) >> 16;
    return (unsigned short)r;
}

__device__ __forceinline__ void gl2lds16(const void* g, void* l) {
    __builtin_amdgcn_global_load_lds(
        (__attribute__((address_space(1))) void*)(g),
        (__attribute__((address_space(3))) void*)(l), 16, 0, 0);
}

// ---- fused conversions: q->bf16, k->padded bf16 (+zero pad rows),
//      W -> Wt2[d][w*512+c] bf16, t[b,j] = conv(k, b_kernel) in f32 ----
__global__ void cvt_all(const float* __restrict__ q, const float* __restrict__ k,
                        unsigned short* __restrict__ qbf, unsigned short* __restrict__ kp,
                        const float* __restrict__ W, unsigned short* __restrict__ Wt2,
                        const float* __restrict__ b_kernel, float* __restrict__ tj) {
    __shared__ float ldsw[1536];
    int blk = blockIdx.x;
    if (blk < 4104) {
        int t = blk * 256 + threadIdx.x;
        if (t < 524288) {                       // q: 8*1024*512 / 8
            const float4* p = (const float4*)q + 2 * (size_t)t;
            float4 a = p[0], b = p[1];
            union { unsigned short s[8]; uint4 v; } o;
            o.s[0]=f2bf(a.x); o.s[1]=f2bf(a.y); o.s[2]=f2bf(a.z); o.s[3]=f2bf(a.w);
            o.s[4]=f2bf(b.x); o.s[5]=f2bf(b.y); o.s[6]=f2bf(b.z); o.s[7]=f2bf(b.w);
            ((uint4*)qbf)[t] = o.v;
        } else if (t < 1048576) {               // k -> padded kp (row j+1)
            int e8 = t - 524288;
            size_t e = (size_t)e8 * 8;
            int b = e8 >> 16;
            int j = (e8 >> 6) & 1023;
            int c = (e8 & 63) * 8;
            const float4* p = (const float4*)(k + e);
            float4 a = p[0], bb = p[1];
            union { unsigned short s[8]; uint4 v; } o;
            o.s[0]=f2bf(a.x); o.s[1]=f2bf(a.y); o.s[2]=f2bf(a.z); o.s[3]=f2bf(a.w);
            o.s[4]=f2bf(bb.x); o.s[5]=f2bf(bb.y); o.s[6]=f2bf(bb.z); o.s[7]=f2bf(bb.w);
            *(uint4*)(kp + ((size_t)(b * 1028 + j + 1) * 512 + c)) = o.v;
        } else if (t < 1050624) {               // zero pad rows 0, 1025..1027
            int z = t - 1048576;
            int b = z >> 8, r = (z >> 6) & 3, ch = z & 63;
            int row = r ? (1024 + r) : 0;
            *(uint4*)(kp + ((size_t)(b * 1028 + row) * 512 + ch * 8)) = make_uint4(0u,0u,0u,0u);
        }
    } else if (blk < 4616) {                    // Wt2 rows 0..511: one d-row per block
        int d = blk - 4104;
        const float4* wrow = (const float4*)(W + (size_t)d * 1536);
        for (int e = threadIdx.x; e < 384; e += 256) {
            float4 v = wrow[e];
            float va[4] = { v.x, v.y, v.z, v.w };
            #pragma unroll
            for (int i = 0; i < 4; i++) {
                int idx = e * 4 + i;            // idx = c*3 + w
                int c = idx / 3, w = idx - c * 3;
                ldsw[w * 512 + c] = va[i];
            }
        }
        __syncthreads();
        for (int p = threadIdx.x; p < 192; p += 256) {
            union { unsigned short s[8]; uint4 v; } o;
            #pragma unroll
            for (int i = 0; i < 8; i++) o.s[i] = f2bf(ldsw[p * 8 + i]);
            *(uint4*)(Wt2 + (size_t)d * 1536 + p * 8) = o.v;
        }
    } else {                                    // t[b,j]: 256 blocks x 32 rows
        int p = blk - 4616;                     // 0..255
        int b = p >> 5, j0r = (p & 31) * 32;
        // stage b_kernel permuted to [w][c] f32
        for (int e = threadIdx.x; e < 1536; e += 256) {
            float v = b_kernel[e];
            int c = e / 3, w = e - c * 3;
            ldsw[w * 512 + c] = v;
        }
        __syncthreads();
        int wave = threadIdx.x >> 6, lane = threadIdx.x & 63;
        // hoist this lane's 24 kernel values
        float bw[3][8];
        #pragma unroll
        for (int w = 0; w < 3; w++)
            #pragma unroll
            for (int i = 0; i < 8; i++) bw[w][i] = ldsw[w * 512 + lane * 8 + i];
        const float* kb = k + (size_t)b * 1024 * 512;
        #pragma unroll
        for (int rr = 0; rr < 8; rr++) {
            int j = j0r + wave * 8 + rr;
            float s = 0.0f;
            #pragma unroll
            for (int w = 0; w < 3; w++) {
                int src = j + w - 1;
                if (src >= 0 && src < 1024) {
                    const float4* kr = (const float4*)(kb + (size_t)src * 512) + lane * 2;
                    float4 a0 = kr[0], a1 = kr[1];
                    s += a0.x*bw[w][0] + a0.y*bw[w][1] + a0.z*bw[w][2] + a0.w*bw[w][3]
                       + a1.x*bw[w][4] + a1.y*bw[w][5] + a1.z*bw[w][6] + a1.w*bw[w][7];
                }
            }
            #pragma unroll
            for (int off = 32; off > 0; off >>= 1) s += __shfl_down(s, off);
            if (lane == 0) tj[b * 1024 + j] = s;
        }
    }
}

// ---- Phase V: V[b*1024+j][n] = bf16( kwin_flat[b,j,:] @ Wt2[n,:]^T + Wb[n] )
//      128m x 64n tiles, 4 waves (2x2), BK=64 dbuf, grid 512 (8b x 8m x 8n),
//      XCD = batch. LDS rows 128B, XOR-swizzle slot^=(row&7). ----
__global__ __launch_bounds__(256) void gemm_V(const unsigned short* __restrict__ kp,
                                              const unsigned short* __restrict__ Wt2,
                                              const float* __restrict__ Wbias,
                                              unsigned short* __restrict__ V) {
    __shared__ unsigned short lds_a[2][128 * 64];   // 2 x 16 KB
    __shared__ unsigned short lds_b[2][64 * 64];    // 2 x 8 KB
    int g = blockIdx.x;                 // 0..511
    int b = g & 7, slot = g >> 3;       // slot 0..63
    int j0 = (slot >> 3) * 128;
    int n0 = (slot & 7) * 64;
    int tid = threadIdx.x, wid = tid >> 6, lane = tid & 63;
    int wm = wid >> 1, wn = wid & 1;
    int crow = lane >> 3;                           // row within 8-row chunk
    int scol = ((lane & 7) ^ crow) * 8;             // inverse-swizzled global col
    const unsigned short* kpb = kp + (size_t)(b * 1028 + j0) * 512;
    floatx4 acc[4][2] = {};

    auto STAGE = [&](int buf, int kk) {
        #pragma unroll
        for (int s = 0; s < 6; ++s) {
            int t = wid * 6 + s;        // 0..23, wave-uniform
            if (t < 16) {               // A: 128 rows x 64k, chunk = 8 rows
                const unsigned short* ga = kpb + (size_t)(t * 8 + crow) * 512 + kk + scol;
                gl2lds16(ga, (char*)lds_a[buf] + t * 1024);
            } else {                    // B: 64 rows x 64k
                int u = t - 16;
                const unsigned short* gb = Wt2 + (size_t)(n0 + u * 8 + crow) * 1536 + kk + scol;
                gl2lds16(gb, (char*)lds_b[buf] + u * 1024);
            }
        }
    };

    STAGE(0, 0);
    __syncthreads();
    int cur = 0;
    int ra = lane & 15, hi = lane >> 4;
    for (int kt = 0; kt < 24; ++kt) {
        if (kt < 23) STAGE(cur ^ 1, (kt + 1) * 64);
        #pragma unroll
        for (int ks = 0; ks < 2; ++ks) {
            s8vec af[4], bfr[2];
            #pragma unroll
            for (int mi = 0; mi < 4; mi++) {
                int R = wm * 64 + mi * 16 + ra;
                af[mi] = *(const s8vec*)((const char*)lds_a[cur] + R * 128 + (((ks << 2) + hi) ^ (R & 7)) * 16);
            }
            #pragma unroll
            for (int ni = 0; ni < 2; ni++) {
                int R = wn * 32 + ni * 16 + ra;
                bfr[ni] = *(const s8vec*)((const char*)lds_b[cur] + R * 128 + (((ks << 2) + hi) ^ (R & 7)) * 16);
            }
            #pragma unroll
            for (int mi = 0; mi < 4; mi++)
                #pragma unroll
                for (int ni = 0; ni < 2; ni++)
                    acc[mi][ni] = __builtin_amdgcn_mfma_f32_16x16x32_bf16(af[mi], bfr[ni], acc[mi][ni], 0, 0, 0);
        }
        if (kt < 23) { __syncthreads(); cur ^= 1; }
    }

    int cl = lane & 15, qd = lane >> 4;
    #pragma unroll
    for (int mi = 0; mi < 4; mi++) {
        #pragma unroll
        for (int ni = 0; ni < 2; ni++) {
            int col = n0 + wn * 32 + ni * 16 + cl;
            float wb = Wbias[col];
            #pragma unroll
            for (int r = 0; r < 4; r++) {
                int m_g = b * 1024 + j0 + wm * 64 + mi * 16 + qd * 4 + r;
                V[(size_t)m_g * 512 + col] = f2bf(acc[mi][ni][r] + wb);
            }
        }
    }
}

// ---- Phase B': out[b,i,j] = sum_d qbf[b,i,d]*V[b,j,d] + t[b,j] + b_bias + bias_b
//      128x128 tiles, 4 waves, BK=64 dbuf, grid 512, XCD = batch. ----
__global__ __launch_bounds__(256) void gemm_QV(const unsigned short* __restrict__ qbf,
                                               const unsigned short* __restrict__ V,
                                               const float* __restrict__ tj,
                                               const float* __restrict__ b_bias,
                                               const float* __restrict__ bias_b,
                                               float* __restrict__ out) {
    __shared__ unsigned short lds_a[2][128 * 64];   // 2 x 16 KB
    __shared__ unsigned short lds_b[2][128 * 64];   // 2 x 16 KB
    int g = blockIdx.x;                 // 0..511
    int b = g & 7, slot = g >> 3;       // slot 0..63
    int i0 = (slot >> 3) * 128;
    int j0 = (slot & 7) * 128;
    int tid = threadIdx.x, wid = tid >> 6, lane = tid & 63;
    int wm = wid >> 1, wn = wid & 1;
    int crow = lane >> 3;
    int scol = ((lane & 7) ^ crow) * 8;
    const unsigned short* Ab = qbf + (size_t)b * 1024 * 512;
    const unsigned short* Bb = V + (size_t)b * 1024 * 512;
    floatx4 acc[4][4] = {};

    auto STAGE = [&](int buf, int kk) {
        #pragma unroll
        for (int s = 0; s < 8; ++s) {
            int t = wid * 8 + s;        // 0..31, wave-uniform
            if (t < 16) {
                const unsigned short* ga = Ab + (size_t)(i0 + t * 8 + crow) * 512 + kk + scol;
                gl2lds16(ga, (char*)lds_a[buf] + t * 1024);
            } else {
                int u = t - 16;
                const unsigned short* gb = Bb + (size_t)(j0 + u * 8 + crow) * 512 + kk + scol;
                gl2lds16(gb, (char*)lds_b[buf] + u * 1024);
            }
        }
    };

    STAGE(0, 0);
    __syncthreads();
    int cur = 0;
    int ra = lane & 15, hi = lane >> 4;
    for (int kt = 0; kt < 8; ++kt) {
        if (kt < 7) STAGE(cur ^ 1, (kt + 1) * 64);
        #pragma unroll
        for (int ks = 0; ks < 2; ++ks) {
            s8vec af[4], bfr[4];
            #pragma unroll
            for (int mi = 0; mi < 4; mi++) {
                int R = wm * 64 + mi * 16 + ra;
                af[mi] = *(const s8vec*)((const char*)lds_a[cur] + R * 128 + (((ks << 2) + hi) ^ (R & 7)) * 16);
            }
            #pragma unroll
            for (int ni = 0; ni < 4; ni++) {
                int R = wn * 64 + ni * 16 + ra;
                bfr[ni] = *(const s8vec*)((const char*)lds_b[cur] + R * 128 + (((ks << 2) + hi) ^ (R & 7)) * 16);
            }
            #pragma unroll
            for (int mi = 0; mi < 4; mi++)
                #pragma unroll
                for (int ni = 0; ni < 4; ni++)
                    acc[mi][ni] = __builtin_amdgcn_mfma_f32_16x16x32_bf16(af[mi], bfr[ni], acc[mi][ni], 0, 0, 0);
        }
        if (kt < 7) { __syncthreads(); cur ^= 1; }
    }

    int cl = lane & 15, qd = lane >> 4;
    float bbsum = b_bias[0] + bias_b[0];
    float tv[4];
    #pragma unroll
    for (int ni = 0; ni < 4; ni++) {
        int j_loc = wn * 64 + ni * 16 + cl;
        tv[ni] = tj[b * 1024 + j0 + j_loc] + bbsum;
    }
    #pragma unroll
    for (int mi = 0; mi < 4; mi++) {
        #pragma unroll
        for (int r = 0; r < 4; r++) {
            int i_g = i0 + wm * 64 + mi * 16 + qd * 4 + r;
            float* orow = out + ((size_t)(b * 1024 + i_g)) * 1024 + j0;
            #pragma unroll
            for (int ni = 0; ni < 4; ni++) {
                int j_loc = wn * 64 + ni * 16 + cl;
                orow[j_loc] = acc[mi][ni][r] + tv[ni];
            }
        }
    }
}

extern "C" void kernel_launch(void* const* d_in, const int* in_sizes, int n_in,
                              void* d_out, int out_size, void* d_ws, size_t ws_size,
                              hipStream_t stream) {
    const float* q        = (const float*)d_in[0];  // (8,1024,512)
    const float* k        = (const float*)d_in[1];  // (8,1024,512)
    const float* W_kernel = (const float*)d_in[2];  // (512,1536)
    const float* b_kernel = (const float*)d_in[3];  // (1536,)
    const float* W_bias   = (const float*)d_in[4];  // (512,1)
    const float* b_bias   = (const float*)d_in[5];  // (1,)
    const float* bias_b   = (const float*)d_in[6];  // (1,)
    float* out = (float*)d_out;                     // (8,1024,1024)

    // workspace carve (bytes):
    //   q_bf 8M | kp 8.03M + 16K headroom | Wt2 1.5M | V 8M | tj 32K
    char* ws = (char*)d_ws;
    unsigned short* q_bf = (unsigned short*)(ws);
    unsigned short* kp   = (unsigned short*)(ws + 8388608);
    unsigned short* Wt2  = (unsigned short*)(ws + 8388608 + 8421376 + 16384);
    unsigned short* V    = (unsigned short*)(ws + 8388608 + 8421376 + 16384 + 1572864);
    float*          tj   = (float*)(ws + 8388608 + 8421376 + 16384 + 1572864 + 8388608);

    cvt_all<<<4872, 256, 0, stream>>>(q, k, q_bf, kp, W_kernel, Wt2, b_kernel, tj);
    gemm_V<<<512, 256, 0, stream>>>(kp, Wt2, W_bias, V);
    gemm_QV<<<512, 256, 0, stream>>>(q_bf, V, tj, b_bias, bias_b, out);
}